// Round 1
// baseline (717.106 us; speedup 1.0000x reference)
//
#include <hip/hip_runtime.h>

// EDTAttention MI355X, round 3: kB re-tiled QBLK 64 -> 32, grid 256 -> 512
// so 2 blocks/CU co-reside (32 waves/CU vs 16). kB was latency-bound at 44%
// occupancy with grid == CU count; LDS halves to 43.6KB so two blocks fit.
// XCD swizzle preserved: bh = idx & 63 keeps all 8 sq-siblings of a bh on
// one XCD sharing L2-resident K/VH/VV.
//
// Index algebra (verified in earlier rounds):
//   Y[b,t,j] = xf @ qkv_w.T + qkv_b,  t = s*256+n, j in [0,256)
//   Q[b,h,s,d]  = Y[b, s*256 +       h*8+ns, j]   d = ns*256+j
//   K[b,h,s,d]  = Y[b, s*256 +  64 + h*8+ns, j]
//   VH[b,h,s,d] = Y[b, s*256 + 128 + h*8+ns, j]
//   VV[b,h,t,d] = Y[b, (h*32+d/64)*256 + 192 + (t/32)*8 + (t%32)/4, (t%4)*64 + d%64]

using half_t = _Float16;
using half8 = __attribute__((ext_vector_type(8))) _Float16;
using f32x4 = __attribute__((ext_vector_type(4))) float;

#define NTOK 524288      // 8*256*256

// ---- workspace layout (bytes) ----
#define WS_Q      0
#define WS_K      67108864
#define WS_VH     134217728
#define WS_VV     201326592
#define WS_XHV    268435456
#define WS_NQ     335544320
#define WS_NK     335609856
#define WS_WH     335675392
#define WS_WP     335708160

// ---------------- weight prep: fp32 -> f16 ----------------
__global__ void kW0(const float* __restrict__ qkv_w, const float* __restrict__ proj_w,
                    half_t* __restrict__ Wh, half_t* __restrict__ Wp) {
    int tid = threadIdx.x;
    for (int i = tid; i < 256 * 64; i += 256) Wh[i] = (half_t)qkv_w[i];
    for (int i = tid; i < 64 * 64; i += 256) Wp[i] = (half_t)proj_w[i];
}

// ---------------- Y-tile MFMA core: acc[mt][i] over 64 tokens x 256 j, K=64 ----
__device__ inline void y_tile_mfma(const float* __restrict__ xb,
                                   const half_t* __restrict__ Wh,
                                   int tbase, int hi, int lo,
                                   f32x4 (&acc)[4][4], int wave, int lane) {
    const int l15 = lane & 15, quad = lane >> 4;
#pragma unroll
    for (int kc = 0; kc < 2; ++kc) {
        const int c = kc * 32 + quad * 8;
        half8 afr[4];
#pragma unroll
        for (int mt = 0; mt < 4; ++mt) {
            int m = mt * 16 + l15;
            int token = tbase + (m >> 3) * hi + (m & 7) * lo;
            const float* p = xb + (size_t)token * 64 + c;
            f32x4 f0 = *(const f32x4*)p;
            f32x4 f1 = *(const f32x4*)(p + 4);
            half8 a;
            a[0] = (half_t)f0[0]; a[1] = (half_t)f0[1]; a[2] = (half_t)f0[2]; a[3] = (half_t)f0[3];
            a[4] = (half_t)f1[0]; a[5] = (half_t)f1[1]; a[6] = (half_t)f1[2]; a[7] = (half_t)f1[3];
            afr[mt] = a;
        }
#pragma unroll
        for (int i = 0; i < 4; ++i) {
            int j = (wave * 4 + i) * 16 + l15;
            half8 bfr = *(const half8*)(Wh + j * 64 + c);
#pragma unroll
            for (int mt = 0; mt < 4; ++mt)
                acc[mt][i] = __builtin_amdgcn_mfma_f32_16x16x32_f16(afr[mt], bfr, acc[mt][i], 0, 0, 0);
        }
    }
}

// row-major dump: ylds[m][j], stride 264
__device__ inline void y_dump_rowmajor(f32x4 (&acc)[4][4], const float* __restrict__ qkv_b,
                                       half_t* ylds, int wave, int lane) {
    const int l15 = lane & 15, quad = lane >> 4;
#pragma unroll
    for (int i = 0; i < 4; ++i) {
        int j = (wave * 4 + i) * 16 + l15;
        float bj = qkv_b[j];
#pragma unroll
        for (int mt = 0; mt < 4; ++mt)
#pragma unroll
            for (int r = 0; r < 4; ++r)
                ylds[(mt * 16 + quad * 4 + r) * 264 + j] = (half_t)(acc[mt][i][r] + bj);
    }
}

// transposed dump: yldsT[j][m], stride 72
__device__ inline void y_dump_transposed(f32x4 (&acc)[4][4], const float* __restrict__ qkv_b,
                                         half_t* yldsT, int wave, int lane) {
    const int l15 = lane & 15, quad = lane >> 4;
#pragma unroll
    for (int i = 0; i < 4; ++i) {
        int j = (wave * 4 + i) * 16 + l15;
        float bj = qkv_b[j];
#pragma unroll
        for (int mt = 0; mt < 4; ++mt)
#pragma unroll
            for (int r = 0; r < 4; ++r)
                yldsT[j * 72 + mt * 16 + quad * 4 + r] = (half_t)(acc[mt][i][r] + bj);
    }
}

// ---------------- A1: Q and K (g=0,1) + norms ----------------
__global__ __launch_bounds__(256) void kA1(const float* __restrict__ x,
                                           const half_t* __restrict__ Wh,
                                           const float* __restrict__ qkv_b,
                                           half_t* __restrict__ Q, half_t* __restrict__ K,
                                           float* __restrict__ normQ, float* __restrict__ normK) {
    __shared__ half_t ylds[64 * 264];
    __shared__ float scr[256];
    int idx = blockIdx.x;
    int sb = idx & 31; idx >>= 5;
    int h = idx & 7; idx >>= 3;
    int g = idx & 1; int b = idx >> 1;
    int s0 = sb * 8;
    int n0 = g * 64 + h * 8;
    int tid = threadIdx.x, wave = tid >> 6, lane = tid & 63;
    const float* xb = x + (size_t)b * 65536 * 64;
    f32x4 acc[4][4];
#pragma unroll
    for (int a = 0; a < 4; ++a)
#pragma unroll
        for (int c = 0; c < 4; ++c) acc[a][c] = {0.f, 0.f, 0.f, 0.f};
    y_tile_mfma(xb, Wh, s0 * 256 + n0, 256, 1, acc, wave, lane);
    y_dump_rowmajor(acc, qkv_b, ylds, wave, lane);
    __syncthreads();
    half_t* dst = (g == 0 ? Q : K) + ((size_t)(b * 8 + h) * 256 + s0) * 2048;
    int ns = tid >> 5, jc = (tid & 31) * 8;
#pragma unroll
    for (int si = 0; si < 8; ++si) {
        half8 v = *(const half8*)&ylds[(si * 8 + ns) * 264 + jc];
        *(half8*)(dst + (size_t)si * 2048 + ns * 256 + jc) = v;
    }
    float sum = 0.f;
#pragma unroll
    for (int nn = 0; nn < 8; ++nn) {
        half8 v = *(const half8*)&ylds[((tid >> 5) * 8 + nn) * 264 + (tid & 31) * 8];
#pragma unroll
        for (int e = 0; e < 8; ++e) { float f = (float)v[e]; sum += f * f; }
    }
    scr[tid] = sum;
    __syncthreads();
    if (tid < 8) {
        float s = 0.f;
        for (int k2 = 0; k2 < 32; ++k2) s += scr[tid * 32 + k2];
        float* nd = (g == 0 ? normQ : normK);
        nd[(b * 8 + h) * 256 + s0 + tid] = s;
    }
}

// ---------------- A2H: V_H (g=2) -> VH[bh][d][t], wide stores ----------------
__global__ __launch_bounds__(256) void kA2H(const float* __restrict__ x,
                                            const half_t* __restrict__ Wh,
                                            const float* __restrict__ qkv_b,
                                            half_t* __restrict__ VH) {
    __shared__ half_t yldsT[256 * 72];
    int idx = blockIdx.x;
    int sb = idx & 3; idx >>= 2;
    int nn = idx & 63; int b = idx >> 6;
    int h = nn >> 3, ns = nn & 7;
    int n = 128 + nn;
    int s0 = sb * 64;
    int tid = threadIdx.x, wave = tid >> 6, lane = tid & 63;
    const float* xb = x + (size_t)b * 65536 * 64;
    f32x4 acc[4][4];
#pragma unroll
    for (int a = 0; a < 4; ++a)
#pragma unroll
        for (int c = 0; c < 4; ++c) acc[a][c] = {0.f, 0.f, 0.f, 0.f};
    y_tile_mfma(xb, Wh, s0 * 256 + n, 2048, 256, acc, wave, lane);  // m == local s
    y_dump_transposed(acc, qkv_b, yldsT, wave, lane);
    __syncthreads();
    int jl = lane >> 3, tc = lane & 7;
    half_t* base = VH + ((size_t)(b * 8 + h) * 2048 + ns * 256) * 256 + s0 + tc * 8;
#pragma unroll
    for (int u = 0; u < 8; ++u) {
        int j = wave * 64 + u * 8 + jl;
        half8 v = *(const half8*)&yldsT[j * 72 + tc * 8];
        *(half8*)(base + (size_t)j * 256) = v;
    }
}

// ---------------- A2V: V_V (g=3) -> VV[bh][d][t] (permuted), wide stores ------
__global__ __launch_bounds__(256) void kA2V(const float* __restrict__ x,
                                            const half_t* __restrict__ Wh,
                                            const float* __restrict__ qkv_b,
                                            half_t* __restrict__ VV) {
    __shared__ half_t yldsT[256 * 72];
    int idx = blockIdx.x;
    int st = idx & 255; int b = idx >> 8;
    int h = st >> 5;
    int tid = threadIdx.x, wave = tid >> 6, lane = tid & 63;
    const float* xb = x + (size_t)b * 65536 * 64;
    f32x4 acc[4][4];
#pragma unroll
    for (int a = 0; a < 4; ++a)
#pragma unroll
        for (int c = 0; c < 4; ++c) acc[a][c] = {0.f, 0.f, 0.f, 0.f};
    y_tile_mfma(xb, Wh, st * 256 + 192, 8, 1, acc, wave, lane);  // m == n-192
    y_dump_transposed(acc, qkv_b, yldsT, wave, lane);
    __syncthreads();
    // element (d = (st&31)*64 + dm, t) <- Y[m][(t&3)*64 + dm],
    //   m = (t>>5)*8 + ((t&31)>>2), t = wave*64 + tc*8 + e
    int dl = lane >> 3, tc = lane & 7;
    int mbase = wave * 16 + (tc >> 2) * 8 + (tc & 3) * 2;
    half_t* base = VV + ((size_t)(b * 8 + h) * 2048 + (st & 31) * 64) * 256 + wave * 64 + tc * 8;
#pragma unroll
    for (int u = 0; u < 8; ++u) {
        int dm = u * 8 + dl;
        half8 v;
#pragma unroll
        for (int e = 0; e < 8; ++e)
            v[e] = yldsT[((e & 3) * 64 + dm) * 72 + mbase + (e >> 2)];
        *(half8*)(base + (size_t)dm * 256) = v;
    }
}

// ---------------- B: fused cosine attention, QBLK=32, 512 blocks x 1024 thr ----
// 2 blocks/CU co-resident (LDS 43648B x2 = 87KB < 160KB, VGPRs ~64) ->
// 32 waves/CU. Grid was the occupancy limiter at QBLK=64 (1 block/CU, 44%).
__global__ __launch_bounds__(1024, 4) void kB(const half_t* __restrict__ Q, const half_t* __restrict__ K,
                                              const half_t* __restrict__ VH, const half_t* __restrict__ VV,
                                              const float* __restrict__ normQ, const float* __restrict__ normK,
                                              const float* __restrict__ temp1, const float* __restrict__ temp2,
                                              half_t* __restrict__ xhv) {
    extern __shared__ char smem[];
    half_t* PH = (half_t*)smem;                  // [32][264]
    half_t* PV = (half_t*)(smem + 16896);        // [32][264]
    float* redA = (float*)(smem + 33792);        // [1024]
    float* redB = (float*)(smem + 37888);        // [1024]
    float* mH  = (float*)(smem + 41984);         // [32]
    float* mV  = (float*)(smem + 42112);         // [32]
    float* rHs = (float*)(smem + 42240);         // [32]
    float* rVs = (float*)(smem + 42368);         // [32]
    float* rq  = (float*)(smem + 42496);         // [32]
    float* rk  = (float*)(smem + 42624);         // [256] -> end 43648

    int idx = blockIdx.x;
    int bh = idx & 63;              // XCD swizzle: same-bh sq-siblings share XCD
    int sqb = idx >> 6;             // 0..7
    int h = bh & 7, b = bh >> 3;
    int sq0 = sqb * 32;
    int tid = threadIdx.x, wave = tid >> 6, lane = tid & 63;
    int l15 = lane & 15, quad = lane >> 4;
    float t1 = temp1[h], t2 = temp2[h];
    const half_t* Qb = Q + (size_t)bh * 256 * 2048;
    const half_t* Kb = K + (size_t)bh * 256 * 2048;
    const half_t* VHb = VH + (size_t)bh * 2048 * 256;
    const half_t* VVb = VV + (size_t)bh * 2048 * 256;

    if (tid < 32) rq[tid] = 1.f / fmaxf(sqrtf(normQ[bh * 256 + sq0 + tid]), 1e-12f);
    if (tid < 256) rk[tid] = 1.f / fmaxf(sqrtf(normK[bh * 256 + tid]), 1e-12f);
    __syncthreads();

    // ---- pass 1: sim = Q.K^T (32 x 256). wave w owns t-tile w*16..+16 ----
    {
        f32x4 acc1[2];
#pragma unroll
        for (int a = 0; a < 2; ++a) acc1[a] = {0.f, 0.f, 0.f, 0.f};
        const int tcol = wave * 16 + l15;
        for (int kc = 0; kc < 64; ++kc) {
            int d = kc * 32 + quad * 8;
            half8 bfr = *(const half8*)(Kb + (size_t)tcol * 2048 + d);
#pragma unroll
            for (int mt = 0; mt < 2; ++mt) {
                half8 afr = *(const half8*)(Qb + (size_t)(sq0 + mt * 16 + l15) * 2048 + d);
                acc1[mt] = __builtin_amdgcn_mfma_f32_16x16x32_f16(afr, bfr, acc1[mt], 0, 0, 0);
            }
        }
        float rkt = rk[tcol];
#pragma unroll
        for (int mt = 0; mt < 2; ++mt)
#pragma unroll
            for (int r = 0; r < 4; ++r) {
                int row = mt * 16 + quad * 4 + r;
                PH[row * 264 + tcol] = (half_t)(acc1[mt][r] * rq[row] * rkt);
            }
    }
    __syncthreads();

    // ---- dual softmax: thread owns (row r_, 8-col chunk c8) ----
    int r_ = tid & 31, c8 = tid >> 5;
    half_t* phrow = &PH[r_ * 264 + c8 * 8];
    half_t* pvrow = &PV[r_ * 264 + c8 * 8];
    float mx = -3.4e38f, mn = 3.4e38f;
#pragma unroll
    for (int i2 = 0; i2 < 8; ++i2) { float v = (float)phrow[i2]; mx = fmaxf(mx, v); mn = fminf(mn, v); }
    redA[tid] = mx; redB[tid] = mn;
    __syncthreads();
    if (tid < 32) {
        float amx = -3.4e38f, amn = 3.4e38f;
#pragma unroll
        for (int q2 = 0; q2 < 32; ++q2) {
            amx = fmaxf(amx, redA[q2 * 32 + tid]);
            amn = fminf(amn, redB[q2 * 32 + tid]);
        }
        mH[tid] = (t1 >= 0.f) ? t1 * amx : t1 * amn;
        mV[tid] = (t2 >= 0.f) ? t2 * amx : t2 * amn;
    }
    __syncthreads();
    float mh = mH[r_], mv = mV[r_];
    float sh = 0.f, sv = 0.f;
#pragma unroll
    for (int i2 = 0; i2 < 8; ++i2) {
        float v = (float)phrow[i2];
        sh += __expf(v * t1 - mh);
        sv += __expf(v * t2 - mv);
    }
    redA[tid] = sh; redB[tid] = sv;
    __syncthreads();
    if (tid < 32) {
        float ash = 0.f, asv = 0.f;
#pragma unroll
        for (int q2 = 0; q2 < 32; ++q2) { ash += redA[q2 * 32 + tid]; asv += redB[q2 * 32 + tid]; }
        rHs[tid] = 1.f / ash;
        rVs[tid] = 1.f / asv;
    }
    __syncthreads();
    float rh = rHs[r_], rv = rVs[r_];
#pragma unroll
    for (int i2 = 0; i2 < 8; ++i2) {
        float v = (float)phrow[i2];
        phrow[i2] = (half_t)(__expf(v * t1 - mh) * rh);
        pvrow[i2] = (half_t)(__expf(v * t2 - mv) * rv);
    }
    __syncthreads();

    // ---- pass 2: x = P_H@V_H + P_V@V_V. wave w owns d-chunks w*64, w*64+1024 ----
#pragma unroll
    for (int i2 = 0; i2 < 2; ++i2) {
        int d0 = wave * 64 + i2 * 1024;
        f32x4 acc2[2][4];
#pragma unroll
        for (int a = 0; a < 2; ++a)
#pragma unroll
            for (int c = 0; c < 4; ++c) acc2[a][c] = {0.f, 0.f, 0.f, 0.f};
        for (int kc = 0; kc < 8; ++kc) {
            int tk = kc * 32 + quad * 8;
            half8 afr[2];
#pragma unroll
            for (int mt = 0; mt < 2; ++mt)
                afr[mt] = *(const half8*)&PH[(mt * 16 + l15) * 264 + tk];
#pragma unroll
            for (int nt = 0; nt < 4; ++nt) {
                half8 bfr = *(const half8*)(VHb + (size_t)(d0 + nt * 16 + l15) * 256 + tk);
#pragma unroll
                for (int mt = 0; mt < 2; ++mt)
                    acc2[mt][nt] = __builtin_amdgcn_mfma_f32_16x16x32_f16(afr[mt], bfr, acc2[mt][nt], 0, 0, 0);
            }
#pragma unroll
            for (int mt = 0; mt < 2; ++mt)
                afr[mt] = *(const half8*)&PV[(mt * 16 + l15) * 264 + tk];
#pragma unroll
            for (int nt = 0; nt < 4; ++nt) {
                half8 bfr = *(const half8*)(VVb + (size_t)(d0 + nt * 16 + l15) * 256 + tk);
#pragma unroll
                for (int mt = 0; mt < 2; ++mt)
                    acc2[mt][nt] = __builtin_amdgcn_mfma_f32_16x16x32_f16(afr[mt], bfr, acc2[mt][nt], 0, 0, 0);
            }
        }
        int db = wave + i2 * 16;   // d0/64 in [0,32)
#pragma unroll
        for (int mt = 0; mt < 2; ++mt)
#pragma unroll
            for (int nt = 0; nt < 4; ++nt) {
                int c = nt * 16 + l15;
#pragma unroll
                for (int r = 0; r < 4; ++r) {
                    int srow = mt * 16 + quad * 4 + r;
                    size_t tk_idx = (size_t)b * 65536 + (size_t)(sq0 + srow) * 256 + h * 32 + db;
                    xhv[tk_idx * 64 + c] = (half_t)acc2[mt][nt][r];
                }
            }
    }
}

// ---------------- C: out = xhv @ proj_w.T + proj_b ----------------
__global__ __launch_bounds__(256) void kC(const half_t* __restrict__ xhv, const half_t* __restrict__ Wp,
                                          const float* __restrict__ proj_b, float* __restrict__ out) {
    __shared__ float ot[64 * 68];
    int tid = threadIdx.x, wave = tid >> 6, lane = tid & 63;
    int l15 = lane & 15, quad = lane >> 4;
    size_t T0 = (size_t)blockIdx.x * 64;
    f32x4 acc[4];
#pragma unroll
    for (int a = 0; a < 4; ++a) acc[a] = {0.f, 0.f, 0.f, 0.f};
#pragma unroll
    for (int kc = 0; kc < 2; ++kc) {
        int c = kc * 32 + quad * 8;
        half8 bfr = *(const half8*)(Wp + (wave * 16 + l15) * 64 + c);
#pragma unroll
        for (int mt = 0; mt < 4; ++mt) {
            half8 afr = *(const half8*)(xhv + (T0 + mt * 16 + l15) * 64 + c);
            acc[mt] = __builtin_amdgcn_mfma_f32_16x16x32_f16(afr, bfr, acc[mt], 0, 0, 0);
        }
    }
    float bj = proj_b[wave * 16 + l15];
#pragma unroll
    for (int mt = 0; mt < 4; ++mt)
#pragma unroll
        for (int r = 0; r < 4; ++r)
            ot[(mt * 16 + quad * 4 + r) * 68 + wave * 16 + l15] = acc[mt][r] + bj;
    __syncthreads();
    int row = tid >> 2;
#pragma unroll
    for (int u = 0; u < 4; ++u) {
        int col = (tid & 3) * 4 + u * 16;
        f32x4 v = *(const f32x4*)&ot[row * 68 + col];
        *(f32x4*)(out + (T0 + row) * 64 + col) = v;
    }
}

extern "C" void kernel_launch(void* const* d_in, const int* in_sizes, int n_in,
                              void* d_out, int out_size, void* d_ws, size_t ws_size,
                              hipStream_t stream) {
    const float* x      = (const float*)d_in[0];
    const float* qkv_w  = (const float*)d_in[1];
    const float* qkv_b  = (const float*)d_in[2];
    const float* proj_w = (const float*)d_in[3];
    const float* proj_b = (const float*)d_in[4];
    const float* temp1  = (const float*)d_in[5];
    const float* temp2  = (const float*)d_in[6];
    char* ws = (char*)d_ws;
    half_t* Q   = (half_t*)(ws + WS_Q);
    half_t* K   = (half_t*)(ws + WS_K);
    half_t* VH  = (half_t*)(ws + WS_VH);
    half_t* VV  = (half_t*)(ws + WS_VV);
    half_t* xhv = (half_t*)(ws + WS_XHV);
    float* normQ = (float*)(ws + WS_NQ);
    float* normK = (float*)(ws + WS_NK);
    half_t* Wh  = (half_t*)(ws + WS_WH);
    half_t* Wp  = (half_t*)(ws + WS_WP);
    float* out = (float*)d_out;

    hipFuncSetAttribute((const void*)kB, hipFuncAttributeMaxDynamicSharedMemorySize, 43648);

    kW0<<<1, 256, 0, stream>>>(qkv_w, proj_w, Wh, Wp);
    kA1<<<4096, 256, 0, stream>>>(x, Wh, qkv_b, Q, K, normQ, normK);
    kA2H<<<2048, 256, 0, stream>>>(x, Wh, qkv_b, VH);
    kA2V<<<2048, 256, 0, stream>>>(x, Wh, qkv_b, VV);
    kB<<<512, 1024, 43648, stream>>>(Q, K, VH, VV, normQ, normK, temp1, temp2, xhv);
    kC<<<8192, 256, 0, stream>>>(xhv, Wp, proj_b, out);
}

// Round 2
// 605.884 us; speedup vs baseline: 1.1836x; 1.1836x over previous
//
#include <hip/hip_runtime.h>

// EDTAttention MI355X, round 4: kB pass-1 rebuilt as LDS-staged double-buffered
// GEMM (global_load_lds width-16, T3 2-phase schedule, XOR-swizzled K/Q tiles).
// Round-1 lesson: occupancy is capped at 4 waves/SIMD by unified VGPR+AGPR
// (128/wave), independent of grid -> attack per-load latency, not wave count.
// QBLK restored to 64 (round-1's QBLK=32 halved AI and regressed 287->340us).
//
// Index algebra (verified in earlier rounds):
//   Y[b,t,j] = xf @ qkv_w.T + qkv_b,  t = s*256+n, j in [0,256)
//   Q[b,h,s,d]  = Y[b, s*256 +       h*8+ns, j]   d = ns*256+j
//   K[b,h,s,d]  = Y[b, s*256 +  64 + h*8+ns, j]
//   VH[b,h,s,d] = Y[b, s*256 + 128 + h*8+ns, j]
//   VV[b,h,t,d] = Y[b, (h*32+d/64)*256 + 192 + (t/32)*8 + (t%32)/4, (t%4)*64 + d%64]

using half_t = _Float16;
using half8 = __attribute__((ext_vector_type(8))) _Float16;
using f32x4 = __attribute__((ext_vector_type(4))) float;

#define NTOK 524288      // 8*256*256

// async global->LDS, 16B per lane, LDS dest = wave-uniform base + lane*16
#define GLDS(g, l) __builtin_amdgcn_global_load_lds( \
    (const __attribute__((address_space(1))) void*)(g), \
    (__attribute__((address_space(3))) void*)(l), 16, 0, 0)

// ---- workspace layout (bytes) ----
#define WS_Q      0
#define WS_K      67108864
#define WS_VH     134217728
#define WS_VV     201326592
#define WS_XHV    268435456
#define WS_NQ     335544320
#define WS_NK     335609856
#define WS_WH     335675392
#define WS_WP     335708160

// ---------------- weight prep: fp32 -> f16 ----------------
__global__ void kW0(const float* __restrict__ qkv_w, const float* __restrict__ proj_w,
                    half_t* __restrict__ Wh, half_t* __restrict__ Wp) {
    int tid = threadIdx.x;
    for (int i = tid; i < 256 * 64; i += 256) Wh[i] = (half_t)qkv_w[i];
    for (int i = tid; i < 64 * 64; i += 256) Wp[i] = (half_t)proj_w[i];
}

// ---------------- Y-tile MFMA core: acc[mt][i] over 64 tokens x 256 j, K=64 ----
__device__ inline void y_tile_mfma(const float* __restrict__ xb,
                                   const half_t* __restrict__ Wh,
                                   int tbase, int hi, int lo,
                                   f32x4 (&acc)[4][4], int wave, int lane) {
    const int l15 = lane & 15, quad = lane >> 4;
#pragma unroll
    for (int kc = 0; kc < 2; ++kc) {
        const int c = kc * 32 + quad * 8;
        half8 afr[4];
#pragma unroll
        for (int mt = 0; mt < 4; ++mt) {
            int m = mt * 16 + l15;
            int token = tbase + (m >> 3) * hi + (m & 7) * lo;
            const float* p = xb + (size_t)token * 64 + c;
            f32x4 f0 = *(const f32x4*)p;
            f32x4 f1 = *(const f32x4*)(p + 4);
            half8 a;
            a[0] = (half_t)f0[0]; a[1] = (half_t)f0[1]; a[2] = (half_t)f0[2]; a[3] = (half_t)f0[3];
            a[4] = (half_t)f1[0]; a[5] = (half_t)f1[1]; a[6] = (half_t)f1[2]; a[7] = (half_t)f1[3];
            afr[mt] = a;
        }
#pragma unroll
        for (int i = 0; i < 4; ++i) {
            int j = (wave * 4 + i) * 16 + l15;
            half8 bfr = *(const half8*)(Wh + j * 64 + c);
#pragma unroll
            for (int mt = 0; mt < 4; ++mt)
                acc[mt][i] = __builtin_amdgcn_mfma_f32_16x16x32_f16(afr[mt], bfr, acc[mt][i], 0, 0, 0);
        }
    }
}

// row-major dump: ylds[m][j], stride 264
__device__ inline void y_dump_rowmajor(f32x4 (&acc)[4][4], const float* __restrict__ qkv_b,
                                       half_t* ylds, int wave, int lane) {
    const int l15 = lane & 15, quad = lane >> 4;
#pragma unroll
    for (int i = 0; i < 4; ++i) {
        int j = (wave * 4 + i) * 16 + l15;
        float bj = qkv_b[j];
#pragma unroll
        for (int mt = 0; mt < 4; ++mt)
#pragma unroll
            for (int r = 0; r < 4; ++r)
                ylds[(mt * 16 + quad * 4 + r) * 264 + j] = (half_t)(acc[mt][i][r] + bj);
    }
}

// transposed dump: yldsT[j][m], stride 72
__device__ inline void y_dump_transposed(f32x4 (&acc)[4][4], const float* __restrict__ qkv_b,
                                         half_t* yldsT, int wave, int lane) {
    const int l15 = lane & 15, quad = lane >> 4;
#pragma unroll
    for (int i = 0; i < 4; ++i) {
        int j = (wave * 4 + i) * 16 + l15;
        float bj = qkv_b[j];
#pragma unroll
        for (int mt = 0; mt < 4; ++mt)
#pragma unroll
            for (int r = 0; r < 4; ++r)
                yldsT[j * 72 + mt * 16 + quad * 4 + r] = (half_t)(acc[mt][i][r] + bj);
    }
}

// ---------------- A1: Q and K (g=0,1) + norms ----------------
__global__ __launch_bounds__(256) void kA1(const float* __restrict__ x,
                                           const half_t* __restrict__ Wh,
                                           const float* __restrict__ qkv_b,
                                           half_t* __restrict__ Q, half_t* __restrict__ K,
                                           float* __restrict__ normQ, float* __restrict__ normK) {
    __shared__ half_t ylds[64 * 264];
    __shared__ float scr[256];
    int idx = blockIdx.x;
    int sb = idx & 31; idx >>= 5;
    int h = idx & 7; idx >>= 3;
    int g = idx & 1; int b = idx >> 1;
    int s0 = sb * 8;
    int n0 = g * 64 + h * 8;
    int tid = threadIdx.x, wave = tid >> 6, lane = tid & 63;
    const float* xb = x + (size_t)b * 65536 * 64;
    f32x4 acc[4][4];
#pragma unroll
    for (int a = 0; a < 4; ++a)
#pragma unroll
        for (int c = 0; c < 4; ++c) acc[a][c] = {0.f, 0.f, 0.f, 0.f};
    y_tile_mfma(xb, Wh, s0 * 256 + n0, 256, 1, acc, wave, lane);
    y_dump_rowmajor(acc, qkv_b, ylds, wave, lane);
    __syncthreads();
    half_t* dst = (g == 0 ? Q : K) + ((size_t)(b * 8 + h) * 256 + s0) * 2048;
    int ns = tid >> 5, jc = (tid & 31) * 8;
#pragma unroll
    for (int si = 0; si < 8; ++si) {
        half8 v = *(const half8*)&ylds[(si * 8 + ns) * 264 + jc];
        *(half8*)(dst + (size_t)si * 2048 + ns * 256 + jc) = v;
    }
    float sum = 0.f;
#pragma unroll
    for (int nn = 0; nn < 8; ++nn) {
        half8 v = *(const half8*)&ylds[((tid >> 5) * 8 + nn) * 264 + (tid & 31) * 8];
#pragma unroll
        for (int e = 0; e < 8; ++e) { float f = (float)v[e]; sum += f * f; }
    }
    scr[tid] = sum;
    __syncthreads();
    if (tid < 8) {
        float s = 0.f;
        for (int k2 = 0; k2 < 32; ++k2) s += scr[tid * 32 + k2];
        float* nd = (g == 0 ? normQ : normK);
        nd[(b * 8 + h) * 256 + s0 + tid] = s;
    }
}

// ---------------- A2H: V_H (g=2) -> VH[bh][d][t], wide stores ----------------
__global__ __launch_bounds__(256) void kA2H(const float* __restrict__ x,
                                            const half_t* __restrict__ Wh,
                                            const float* __restrict__ qkv_b,
                                            half_t* __restrict__ VH) {
    __shared__ half_t yldsT[256 * 72];
    int idx = blockIdx.x;
    int sb = idx & 3; idx >>= 2;
    int nn = idx & 63; int b = idx >> 6;
    int h = nn >> 3, ns = nn & 7;
    int n = 128 + nn;
    int s0 = sb * 64;
    int tid = threadIdx.x, wave = tid >> 6, lane = tid & 63;
    const float* xb = x + (size_t)b * 65536 * 64;
    f32x4 acc[4][4];
#pragma unroll
    for (int a = 0; a < 4; ++a)
#pragma unroll
        for (int c = 0; c < 4; ++c) acc[a][c] = {0.f, 0.f, 0.f, 0.f};
    y_tile_mfma(xb, Wh, s0 * 256 + n, 2048, 256, acc, wave, lane);  // m == local s
    y_dump_transposed(acc, qkv_b, yldsT, wave, lane);
    __syncthreads();
    int jl = lane >> 3, tc = lane & 7;
    half_t* base = VH + ((size_t)(b * 8 + h) * 2048 + ns * 256) * 256 + s0 + tc * 8;
#pragma unroll
    for (int u = 0; u < 8; ++u) {
        int j = wave * 64 + u * 8 + jl;
        half8 v = *(const half8*)&yldsT[j * 72 + tc * 8];
        *(half8*)(base + (size_t)j * 256) = v;
    }
}

// ---------------- A2V: V_V (g=3) -> VV[bh][d][t] (permuted), wide stores ------
__global__ __launch_bounds__(256) void kA2V(const float* __restrict__ x,
                                            const half_t* __restrict__ Wh,
                                            const float* __restrict__ qkv_b,
                                            half_t* __restrict__ VV) {
    __shared__ half_t yldsT[256 * 72];
    int idx = blockIdx.x;
    int st = idx & 255; int b = idx >> 8;
    int h = st >> 5;
    int tid = threadIdx.x, wave = tid >> 6, lane = tid & 63;
    const float* xb = x + (size_t)b * 65536 * 64;
    f32x4 acc[4][4];
#pragma unroll
    for (int a = 0; a < 4; ++a)
#pragma unroll
        for (int c = 0; c < 4; ++c) acc[a][c] = {0.f, 0.f, 0.f, 0.f};
    y_tile_mfma(xb, Wh, st * 256 + 192, 8, 1, acc, wave, lane);  // m == n-192
    y_dump_transposed(acc, qkv_b, yldsT, wave, lane);
    __syncthreads();
    // element (d = (st&31)*64 + dm, t) <- Y[m][(t&3)*64 + dm],
    //   m = (t>>5)*8 + ((t&31)>>2), t = wave*64 + tc*8 + e
    int dl = lane >> 3, tc = lane & 7;
    int mbase = wave * 16 + (tc >> 2) * 8 + (tc & 3) * 2;
    half_t* base = VV + ((size_t)(b * 8 + h) * 2048 + (st & 31) * 64) * 256 + wave * 64 + tc * 8;
#pragma unroll
    for (int u = 0; u < 8; ++u) {
        int dm = u * 8 + dl;
        half8 v;
#pragma unroll
        for (int e = 0; e < 8; ++e)
            v[e] = yldsT[((e & 3) * 64 + dm) * 72 + mbase + (e >> 2)];
        *(half8*)(base + (size_t)dm * 256) = v;
    }
}

// ---------------- B: fused cosine attention, QBLK=64, 256 blocks x 1024 thr ----
// Pass 1 = LDS-staged double-buffered GEMM (64x256xK2048):
//   per K-step (BK=64 halfs): stage Q[64][64] (8KB) + K[256][64] (32KB) via
//   global_load_lds width-16 (zero VGPR for in-flight loads), XOR-swizzled
//   (source pre-swizzle + swizzled ds_read_b128, linear LDS dest), 2-phase
//   schedule: STAGE(next buf) issued BEFORE compute(cur), one barrier/step.
// LDS total 160000B -> 1 block/CU (VGPR cap forces that anyway: acc2 64 AGPR
// + ~64 VGPR = 128/wave = 4 waves/SIMD).
__global__ __launch_bounds__(1024, 4) void kB(const half_t* __restrict__ Q, const half_t* __restrict__ K,
                                              const half_t* __restrict__ VH, const half_t* __restrict__ VV,
                                              const float* __restrict__ normQ, const float* __restrict__ normK,
                                              const float* __restrict__ temp1, const float* __restrict__ temp2,
                                              half_t* __restrict__ xhv) {
    extern __shared__ char smem[];
    char* Ks0 = smem;                            // [256][64] halfs, 32768B
    char* Ks1 = smem + 32768;                    // 32768B
    char* Qs0 = smem + 65536;                    // [64][64] halfs, 8192B
    char* Qs1 = smem + 73728;                    // 8192B
    half_t* PH = (half_t*)(smem + 81920);        // [64][264]
    half_t* PV = (half_t*)(smem + 115712);       // [64][264] -> 149504
    float* redA = (float*)(smem + 149504);       // [1024]
    float* redB = (float*)(smem + 153600);       // [1024]
    float* mH  = (float*)(smem + 157696);        // [64]
    float* mV  = (float*)(smem + 157952);        // [64]
    float* rHs = (float*)(smem + 158208);        // [64]
    float* rVs = (float*)(smem + 158464);        // [64]
    float* rq  = (float*)(smem + 158720);        // [64]
    float* rk  = (float*)(smem + 158976);        // [256] -> end 160000

    int idx = blockIdx.x;
    int bh = idx & 63;              // XCD swizzle: same-bh sq-siblings share XCD
    int sqb = idx >> 6;             // 0..3
    int h = bh & 7, b = bh >> 3;
    int sq0 = sqb * 64;
    int tid = threadIdx.x, wave = tid >> 6, lane = tid & 63;
    int l15 = lane & 15, quad = lane >> 4;
    float t1 = temp1[h], t2 = temp2[h];
    const half_t* Qb = Q + (size_t)bh * 256 * 2048;
    const half_t* Kb = K + (size_t)bh * 256 * 2048;
    const half_t* VHb = VH + (size_t)bh * 2048 * 256;
    const half_t* VVb = VV + (size_t)bh * 2048 * 256;

    if (tid < 64) rq[tid] = 1.f / fmaxf(sqrtf(normQ[bh * 256 + sq0 + tid]), 1e-12f);
    if (tid < 256) rk[tid] = 1.f / fmaxf(sqrtf(normK[bh * 256 + tid]), 1e-12f);

    // ---- pass 1: sim = Q.K^T (64 x 256), LDS-staged. wave w owns t-tile w*16 ----
    {
        const int l7 = lane & 7, l8 = lane >> 3;
        // pre-swizzled global source: LDS slot (row r, s) holds global col16 s^(r&7).
        // lane writes slot l7 of row (chunk*8 + l8); r&7 == l8&7 (chunks 8-aligned).
        const int swzh = (l7 ^ (l8 & 7)) * 8;     // halfs offset within 64-half row
        const half_t* gK0 = Kb + (size_t)(wave * 8 + l8) * 2048 + swzh;         // rows [w*8, +8)
        const half_t* gK1 = Kb + (size_t)(128 + wave * 8 + l8) * 2048 + swzh;   // rows [128+w*8, +8)
        const half_t* gQ  = Qb + (size_t)(sq0 + (wave & 7) * 8 + l8) * 2048 + swzh;

        auto STAGE = [&](int kk, char* KsB, char* QsB) {
            const int off = kk * 64;              // BK=64 halfs per step
            GLDS(gK0 + off, KsB + wave * 1024);
            GLDS(gK1 + off, KsB + 16384 + wave * 1024);
            if (wave < 8) GLDS(gQ + off, QsB + wave * 1024);
        };

        f32x4 acc1[4];
#pragma unroll
        for (int a = 0; a < 4; ++a) acc1[a] = {0.f, 0.f, 0.f, 0.f};
        const int tcol = wave * 16 + l15;
        const int ts7 = tcol & 7;

        auto COMPUTE = [&](const char* KsB_, const char* QsB_) {
            const half_t* KsB = (const half_t*)KsB_;
            const half_t* QsB = (const half_t*)QsB_;
#pragma unroll
            for (int sub = 0; sub < 2; ++sub) {
                int c16 = sub * 4 + quad;         // 16B-slot index = d-slice
                half8 bfr = *(const half8*)(KsB + tcol * 64 + (c16 ^ ts7) * 8);
#pragma unroll
                for (int mt = 0; mt < 4; ++mt) {
                    int m = mt * 16 + l15;
                    half8 afr = *(const half8*)(QsB + m * 64 + (c16 ^ (m & 7)) * 8);
                    acc1[mt] = __builtin_amdgcn_mfma_f32_16x16x32_f16(afr, bfr, acc1[mt], 0, 0, 0);
                }
            }
        };

        STAGE(0, Ks0, Qs0);
        __syncthreads();                          // drains vmcnt -> buf0 ready (also rq/rk)
        for (int kk = 0; kk < 32; kk += 2) {
            if (kk + 1 < 32) STAGE(kk + 1, Ks1, Qs1);
            COMPUTE(Ks0, Qs0);
            __syncthreads();                      // buf1 staged + buf0 consumed
            if (kk + 2 < 32) STAGE(kk + 2, Ks0, Qs0);
            COMPUTE(Ks1, Qs1);
            __syncthreads();
        }
        float rkt = rk[tcol];
#pragma unroll
        for (int mt = 0; mt < 4; ++mt)
#pragma unroll
            for (int r = 0; r < 4; ++r) {
                int row = mt * 16 + quad * 4 + r;
                PH[row * 264 + tcol] = (half_t)(acc1[mt][r] * rq[row] * rkt);
            }
    }
    __syncthreads();

    // ---- dual softmax: thread owns (row r_, 16-col chunk c16) ----
    int r_ = tid & 63, cc = tid >> 6;
    half_t* phrow = &PH[r_ * 264 + cc * 16];
    half_t* pvrow = &PV[r_ * 264 + cc * 16];
    float mx = -3.4e38f, mn = 3.4e38f;
#pragma unroll
    for (int i2 = 0; i2 < 16; ++i2) { float v = (float)phrow[i2]; mx = fmaxf(mx, v); mn = fminf(mn, v); }
    redA[tid] = mx; redB[tid] = mn;
    __syncthreads();
    if (tid < 64) {
        float amx = -3.4e38f, amn = 3.4e38f;
#pragma unroll
        for (int q2 = 0; q2 < 16; ++q2) {
            amx = fmaxf(amx, redA[q2 * 64 + tid]);
            amn = fminf(amn, redB[q2 * 64 + tid]);
        }
        mH[tid] = (t1 >= 0.f) ? t1 * amx : t1 * amn;
        mV[tid] = (t2 >= 0.f) ? t2 * amx : t2 * amn;
    }
    __syncthreads();
    float mh = mH[r_], mv = mV[r_];
    float sh = 0.f, sv = 0.f;
#pragma unroll
    for (int i2 = 0; i2 < 16; ++i2) {
        float v = (float)phrow[i2];
        sh += __expf(v * t1 - mh);
        sv += __expf(v * t2 - mv);
    }
    redA[tid] = sh; redB[tid] = sv;
    __syncthreads();
    if (tid < 64) {
        float ash = 0.f, asv = 0.f;
#pragma unroll
        for (int q2 = 0; q2 < 16; ++q2) { ash += redA[q2 * 64 + tid]; asv += redB[q2 * 64 + tid]; }
        rHs[tid] = 1.f / ash;
        rVs[tid] = 1.f / asv;
    }
    __syncthreads();
    float rh = rHs[r_], rv = rVs[r_];
#pragma unroll
    for (int i2 = 0; i2 < 16; ++i2) {
        float v = (float)phrow[i2];
        phrow[i2] = (half_t)(__expf(v * t1 - mh) * rh);
        pvrow[i2] = (half_t)(__expf(v * t2 - mv) * rv);
    }
    __syncthreads();

    // ---- pass 2: x = P_H@V_H + P_V@V_V. wave w owns d-chunks w*64, w*64+1024 ----
#pragma unroll
    for (int i2 = 0; i2 < 2; ++i2) {
        int d0 = wave * 64 + i2 * 1024;
        f32x4 acc2[4][4];
#pragma unroll
        for (int a = 0; a < 4; ++a)
#pragma unroll
            for (int c = 0; c < 4; ++c) acc2[a][c] = {0.f, 0.f, 0.f, 0.f};
        for (int kc = 0; kc < 8; ++kc) {
            int tk = kc * 32 + quad * 8;
            half8 afr[4];
#pragma unroll
            for (int mt = 0; mt < 4; ++mt)
                afr[mt] = *(const half8*)&PH[(mt * 16 + l15) * 264 + tk];
#pragma unroll
            for (int nt = 0; nt < 4; ++nt) {
                half8 bfr = *(const half8*)(VHb + (size_t)(d0 + nt * 16 + l15) * 256 + tk);
#pragma unroll
                for (int mt = 0; mt < 4; ++mt)
                    acc2[mt][nt] = __builtin_amdgcn_mfma_f32_16x16x32_f16(afr[mt], bfr, acc2[mt][nt], 0, 0, 0);
            }
#pragma unroll
            for (int mt = 0; mt < 4; ++mt)
                afr[mt] = *(const half8*)&PV[(mt * 16 + l15) * 264 + tk];
#pragma unroll
            for (int nt = 0; nt < 4; ++nt) {
                half8 bfr = *(const half8*)(VVb + (size_t)(d0 + nt * 16 + l15) * 256 + tk);
#pragma unroll
                for (int mt = 0; mt < 4; ++mt)
                    acc2[mt][nt] = __builtin_amdgcn_mfma_f32_16x16x32_f16(afr[mt], bfr, acc2[mt][nt], 0, 0, 0);
            }
        }
        int db = wave + i2 * 16;   // d0/64 in [0,32)
#pragma unroll
        for (int mt = 0; mt < 4; ++mt)
#pragma unroll
            for (int nt = 0; nt < 4; ++nt) {
                int c = nt * 16 + l15;
#pragma unroll
                for (int r = 0; r < 4; ++r) {
                    int srow = mt * 16 + quad * 4 + r;
                    size_t tk_idx = (size_t)b * 65536 + (size_t)(sq0 + srow) * 256 + h * 32 + db;
                    xhv[tk_idx * 64 + c] = (half_t)acc2[mt][nt][r];
                }
            }
    }
}

// ---------------- C: out = xhv @ proj_w.T + proj_b ----------------
__global__ __launch_bounds__(256) void kC(const half_t* __restrict__ xhv, const half_t* __restrict__ Wp,
                                          const float* __restrict__ proj_b, float* __restrict__ out) {
    __shared__ float ot[64 * 68];
    int tid = threadIdx.x, wave = tid >> 6, lane = tid & 63;
    int l15 = lane & 15, quad = lane >> 4;
    size_t T0 = (size_t)blockIdx.x * 64;
    f32x4 acc[4];
#pragma unroll
    for (int a = 0; a < 4; ++a) acc[a] = {0.f, 0.f, 0.f, 0.f};
#pragma unroll
    for (int kc = 0; kc < 2; ++kc) {
        int c = kc * 32 + quad * 8;
        half8 bfr = *(const half8*)(Wp + (wave * 16 + l15) * 64 + c);
#pragma unroll
        for (int mt = 0; mt < 4; ++mt) {
            half8 afr = *(const half8*)(xhv + (T0 + mt * 16 + l15) * 64 + c);
            acc[mt] = __builtin_amdgcn_mfma_f32_16x16x32_f16(afr, bfr, acc[mt], 0, 0, 0);
        }
    }
    float bj = proj_b[wave * 16 + l15];
#pragma unroll
    for (int mt = 0; mt < 4; ++mt)
#pragma unroll
        for (int r = 0; r < 4; ++r)
            ot[(mt * 16 + quad * 4 + r) * 68 + wave * 16 + l15] = acc[mt][r] + bj;
    __syncthreads();
    int row = tid >> 2;
#pragma unroll
    for (int u = 0; u < 4; ++u) {
        int col = (tid & 3) * 4 + u * 16;
        f32x4 v = *(const f32x4*)&ot[row * 68 + col];
        *(f32x4*)(out + (T0 + row) * 64 + col) = v;
    }
}

extern "C" void kernel_launch(void* const* d_in, const int* in_sizes, int n_in,
                              void* d_out, int out_size, void* d_ws, size_t ws_size,
                              hipStream_t stream) {
    const float* x      = (const float*)d_in[0];
    const float* qkv_w  = (const float*)d_in[1];
    const float* qkv_b  = (const float*)d_in[2];
    const float* proj_w = (const float*)d_in[3];
    const float* proj_b = (const float*)d_in[4];
    const float* temp1  = (const float*)d_in[5];
    const float* temp2  = (const float*)d_in[6];
    char* ws = (char*)d_ws;
    half_t* Q   = (half_t*)(ws + WS_Q);
    half_t* K   = (half_t*)(ws + WS_K);
    half_t* VH  = (half_t*)(ws + WS_VH);
    half_t* VV  = (half_t*)(ws + WS_VV);
    half_t* xhv = (half_t*)(ws + WS_XHV);
    float* normQ = (float*)(ws + WS_NQ);
    float* normK = (float*)(ws + WS_NK);
    half_t* Wh  = (half_t*)(ws + WS_WH);
    half_t* Wp  = (half_t*)(ws + WS_WP);
    float* out = (float*)d_out;

    hipFuncSetAttribute((const void*)kB, hipFuncAttributeMaxDynamicSharedMemorySize, 160000);

    kW0<<<1, 256, 0, stream>>>(qkv_w, proj_w, Wh, Wp);
    kA1<<<4096, 256, 0, stream>>>(x, Wh, qkv_b, Q, K, normQ, normK);
    kA2H<<<2048, 256, 0, stream>>>(x, Wh, qkv_b, VH);
    kA2V<<<2048, 256, 0, stream>>>(x, Wh, qkv_b, VV);
    kB<<<256, 1024, 160000, stream>>>(Q, K, VH, VV, normQ, normK, temp1, temp2, xhv);
    kC<<<8192, 256, 0, stream>>>(xhv, Wp, proj_b, out);
}